// Round 1
// baseline (162.254 us; speedup 1.0000x reference)
//
#include <hip/hip_runtime.h>
#include <hip/hip_bf16.h>

// B=32, N=128, K=16, F_ATOM=F_NEI=256, D=256, H=4, DK=64
// Inputs (fp32): atom_feature[4096,256], atom_neighbor_feature[65536,256],
//   softmax_mask[4096,16], attend_mask[4096,16], W_a[256,256], b_a[256],
//   W_n[256,256], b_n[256], w_align[64], b_align[1], ln_gamma[256], ln_beta[256]
// Output (fp32): [4096, 256]

typedef float f32x4 __attribute__((ext_vector_type(4)));
typedef __bf16 bf16x8 __attribute__((ext_vector_type(8)));

__device__ __forceinline__ unsigned short f2bf(float x) {
    unsigned int u = __float_as_uint(x);
    u += 0x7FFFu + ((u >> 16) & 1u);   // round-to-nearest-even truncation
    return (unsigned short)(u >> 16);
}

// C[32 rows][256 d] = src(32x256 fp32, contiguous rows) * W^T
// W: [256 d][256 f] bf16 row-major (read straight from L2).
// Stages src into lds_a (32*512 bytes) as bf16 with XOR swizzle
// (byte ^= (row&7)<<4) to kill the 512B-stride bank conflict on ds_read_b128.
// One __syncthreads() between stage and compute. acc must be pre-zeroed.
__device__ __forceinline__ void gemm_tile(const float4* __restrict__ src4,
                                          const unsigned short* __restrict__ w,
                                          char* lds_a, f32x4 acc[2][4]) {
    const int tid = threadIdx.x;
#pragma unroll
    for (int j = 0; j < 8; ++j) {
        const int idx4 = tid + j * 256;      // 2048 float4s = 32 rows x 256 f
        const float4 v = src4[idx4];         // fully coalesced 1KB/wave
        const int r = idx4 >> 6;             // row 0..31
        const int byt = (idx4 & 63) * 8;     // byte offset of 4 bf16 within row
        ushort4 h;
        h.x = f2bf(v.x); h.y = f2bf(v.y); h.z = f2bf(v.z); h.w = f2bf(v.w);
        *(ushort4*)(lds_a + r * 512 + (byt ^ ((r & 7) << 4))) = h;
    }
    __syncthreads();
    const int lane = tid & 63;
    const int wv   = tid >> 6;    // wave id: owns d range [wv*64, wv*64+64)
    const int l15  = lane & 15;
    const int lg   = lane >> 4;   // k-group 0..3
#pragma unroll
    for (int kk = 0; kk < 8; ++kk) {         // K = 256 in steps of 32
        const int f = kk * 32 + lg * 8;
        bf16x8 afrag[2];
#pragma unroll
        for (int mi = 0; mi < 2; ++mi) {
            const int r = mi * 16 + l15;
            afrag[mi] = *(const bf16x8*)(lds_a + r * 512 + ((f * 2) ^ ((r & 7) << 4)));
        }
#pragma unroll
        for (int ni = 0; ni < 4; ++ni) {
            const int d = wv * 64 + ni * 16 + l15;
            const bf16x8 bfrag = *(const bf16x8*)(w + d * 256 + f); // K-contiguous 16B
#pragma unroll
            for (int mi = 0; mi < 2; ++mi)
                acc[mi][ni] = __builtin_amdgcn_mfma_f32_16x16x32_bf16(
                    afrag[mi], bfrag, acc[mi][ni], 0, 0, 0);
        }
    }
}

// ---------------- kernel 0: convert weights to bf16 ----------------
__global__ __launch_bounds__(256) void conv_w(const float4* __restrict__ wa,
                                              const float4* __restrict__ wn,
                                              ushort4* __restrict__ owa,
                                              ushort4* __restrict__ own) {
    const int i = blockIdx.x * 256 + threadIdx.x;   // 16384 float4s each
    const float4 a = wa[i], n = wn[i];
    ushort4 ha, hn;
    ha.x = f2bf(a.x); ha.y = f2bf(a.y); ha.z = f2bf(a.z); ha.w = f2bf(a.w);
    hn.x = f2bf(n.x); hn.y = f2bf(n.y); hn.z = f2bf(n.z); hn.w = f2bf(n.w);
    owa[i] = ha; own[i] = hn;
}

// ---------------- kernel 1: af = atom_feature @ W_a^T + b_a ----------------
__global__ __launch_bounds__(256) void proj_atoms(const float* __restrict__ atomf,
                                                  const unsigned short* __restrict__ wa,
                                                  const float* __restrict__ b_a,
                                                  float* __restrict__ af) {
    __shared__ char lds[32 * 512];
    f32x4 acc[2][4];
#pragma unroll
    for (int mi = 0; mi < 2; ++mi)
#pragma unroll
        for (int ni = 0; ni < 4; ++ni)
#pragma unroll
            for (int j = 0; j < 4; ++j) acc[mi][ni][j] = 0.f;
    gemm_tile((const float4*)(atomf + blockIdx.x * 32 * 256), wa, lds, acc);
    const int lane = threadIdx.x & 63, wv = threadIdx.x >> 6;
    const int l15 = lane & 15, lg = lane >> 4;
#pragma unroll
    for (int ni = 0; ni < 4; ++ni) {
        const int d = wv * 64 + ni * 16 + l15;
        const float b = b_a[d];
#pragma unroll
        for (int mi = 0; mi < 2; ++mi)
#pragma unroll
            for (int j = 0; j < 4; ++j)
                af[(blockIdx.x * 32 + mi * 16 + lg * 4 + j) * 256 + d] = acc[mi][ni][j] + b;
    }
}

// ---------------- kernel 2: fused neighbor proj + GATv2 attn + LN ----------------
struct Smem2 {
    union {
        char  a[32 * 512];      // bf16 staged neighbor tile (K-loop phase)
        float nf[32][260];      // projected neighbors + bias (epilogue phase), +4 pad
    } u;
    float af[2][256];
    float wal[64];
    float attw[2][4][16];
    float red[4][2][2];         // [wave][atom][sum, sumsq]
};

__global__ __launch_bounds__(256) void gat_fused(
        const float* __restrict__ nei, const float* __restrict__ afbuf,
        const unsigned short* __restrict__ wn, const float* __restrict__ b_n,
        const float* __restrict__ smask, const float* __restrict__ amask,
        const float* __restrict__ w_align, const float* __restrict__ b_align,
        const float* __restrict__ gamma, const float* __restrict__ beta,
        float* __restrict__ out) {
    __shared__ Smem2 s;
    const int tid = threadIdx.x;
    const int p = blockIdx.x;            // pair of atoms: bn = 2p, 2p+1

    // stage af rows + w_align (covered by gemm_tile's barrier)
    s.af[0][tid] = afbuf[p * 512 + tid];
    s.af[1][tid] = afbuf[p * 512 + 256 + tid];
    if (tid < 64) s.wal[tid] = w_align[tid];

    f32x4 acc[2][4];
#pragma unroll
    for (int mi = 0; mi < 2; ++mi)
#pragma unroll
        for (int ni = 0; ni < 4; ++ni)
#pragma unroll
            for (int j = 0; j < 4; ++j) acc[mi][ni][j] = 0.f;

    gemm_tile((const float4*)(nei + (size_t)p * 32 * 256), wn, s.u.a, acc);
    __syncthreads();   // all waves done reading lds_a before nf overwrites it

    const int lane = tid & 63, wv = tid >> 6, l15 = lane & 15, lg = lane >> 4;
    // acc -> nf LDS (+ bias). C/D map: row = mi*16 + lg*4 + j, col = l15.
#pragma unroll
    for (int ni = 0; ni < 4; ++ni) {
        const int d = wv * 64 + ni * 16 + l15;
        const float bn = b_n[d];
#pragma unroll
        for (int mi = 0; mi < 2; ++mi)
#pragma unroll
            for (int j = 0; j < 4; ++j)
                s.u.nf[mi * 16 + lg * 4 + j][d] = acc[mi][ni][j] + bn;
    }
    __syncthreads();

    // scores + masked softmax over k (16 lanes per (atom, head))
    if (tid < 128) {
        const int a = tid >> 6, h = (tid >> 4) & 3, k = tid & 15;
        const float* afr = &s.af[a][h * 64];
        const float* nfr = &s.u.nf[a * 16 + k][h * 64];
        float sc = 0.f;
#pragma unroll
        for (int dk = 0; dk < 64; ++dk) {
            float x = afr[dk] + nfr[dk];
            x = (x >= 0.f) ? x : 0.2f * x;    // LeakyReLU slope 0.2
            sc = fmaf(x, s.wal[dk], sc);
        }
        sc += b_align[0] + smask[p * 32 + a * 16 + k];
        float mx = sc;
#pragma unroll
        for (int o = 1; o < 16; o <<= 1) mx = fmaxf(mx, __shfl_xor(mx, o));
        const float e = __expf(sc - mx);
        float sm = e;
#pragma unroll
        for (int o = 1; o < 16; o <<= 1) sm += __shfl_xor(sm, o);
        s.attw[a][h][k] = (e / sm) * amask[p * 32 + a * 16 + k];
    }
    __syncthreads();

    // ctx = sum_k attw * nf, then LayerNorm over d=256
    const int d = tid;
    const float g = gamma[d], be = beta[d];
    const int h = d >> 6;
#pragma unroll
    for (int a = 0; a < 2; ++a) {
        float c = 0.f;
#pragma unroll
        for (int k = 0; k < 16; ++k)
            c = fmaf(s.attw[a][h][k], s.u.nf[a * 16 + k][d], c);
        float sm = c, sq = c * c;
#pragma unroll
        for (int o = 1; o < 64; o <<= 1) {
            sm += __shfl_xor(sm, o);
            sq += __shfl_xor(sq, o);
        }
        if (lane == 0) { s.red[wv][a][0] = sm; s.red[wv][a][1] = sq; }
        __syncthreads();
        float ts = 0.f, tq = 0.f;
#pragma unroll
        for (int q = 0; q < 4; ++q) { ts += s.red[q][a][0]; tq += s.red[q][a][1]; }
        const float mu = ts * (1.f / 256.f);
        float var = tq * (1.f / 256.f) - mu * mu;
        var = fmaxf(var, 0.f);
        out[(p * 2 + a) * 256 + d] = (c - mu) * rsqrtf(var + 1e-5f) * g + be;
        __syncthreads();
    }
}

extern "C" void kernel_launch(void* const* d_in, const int* in_sizes, int n_in,
                              void* d_out, int out_size, void* d_ws, size_t ws_size,
                              hipStream_t stream) {
    const float* atomf = (const float*)d_in[0];
    const float* nei   = (const float*)d_in[1];
    const float* smask = (const float*)d_in[2];
    const float* amask = (const float*)d_in[3];
    const float* Wa    = (const float*)d_in[4];
    const float* ba    = (const float*)d_in[5];
    const float* Wn    = (const float*)d_in[6];
    const float* bn    = (const float*)d_in[7];
    const float* wal   = (const float*)d_in[8];
    const float* bal   = (const float*)d_in[9];
    const float* gam   = (const float*)d_in[10];
    const float* bet   = (const float*)d_in[11];
    float* out = (float*)d_out;

    char* ws = (char*)d_ws;
    float*          af_buf = (float*)ws;                              // 4 MiB
    unsigned short* wa_bf  = (unsigned short*)(ws + 4194304);         // 128 KiB
    unsigned short* wn_bf  = (unsigned short*)(ws + 4194304 + 131072);// 128 KiB

    hipLaunchKernelGGL(conv_w, dim3(64), dim3(256), 0, stream,
                       (const float4*)Wa, (const float4*)Wn,
                       (ushort4*)wa_bf, (ushort4*)wn_bf);
    hipLaunchKernelGGL(proj_atoms, dim3(128), dim3(256), 0, stream,
                       atomf, wa_bf, ba, af_buf);
    hipLaunchKernelGGL(gat_fused, dim3(2048), dim3(256), 0, stream,
                       nei, af_buf, wn_bf, bn, smask, amask, wal, bal, gam, bet, out);
}

// Round 4
// 142.848 us; speedup vs baseline: 1.1358x; 1.1358x over previous
//
#include <hip/hip_runtime.h>
#include <hip/hip_bf16.h>

// B=32, N=128, K=16, F=D=256, H=4, DK=64
// Inputs (fp32): atom_feature[4096,256], atom_neighbor_feature[65536,256],
//   softmax_mask[4096,16], attend_mask[4096,16], W_a[256,256], b_a[256],
//   W_n[256,256], b_n[256], w_align[64], b_align[1], ln_gamma[256], ln_beta[256]
// Output (fp32): [4096, 256]

typedef float f32x4 __attribute__((ext_vector_type(4)));
typedef __bf16 bf16x8 __attribute__((ext_vector_type(8)));

__device__ __forceinline__ unsigned short f2bf(float x) {
    unsigned int u = __float_as_uint(x);
    u += 0x7FFFu + ((u >> 16) & 1u);   // round-to-nearest-even
    return (unsigned short)(u >> 16);
}

// ---------------- kernel 0: convert + permute weights to MFMA B-frag order ----
// Fragment chunk c (16B = 8 bf16) for (wv,kk,ni,lane):
//   c = ((wv*8 + kk)*4 + ni)*64 + lane
//   holds W[d = wv*64 + ni*16 + (lane&15)][f = kk*32 + (lane>>4)*8 .. +8)
__global__ __launch_bounds__(256) void conv_w(const float* __restrict__ wa,
                                              const float* __restrict__ wn,
                                              unsigned short* __restrict__ owa,
                                              unsigned short* __restrict__ own) {
    const int g = blockIdx.x * 256 + threadIdx.x;     // 0..16383
    const float* src = (g & 8192) ? wn : wa;
    unsigned short* dst = (g & 8192) ? own : owa;
    const int c = g & 8191;
    const int lane = c & 63, ni = (c >> 6) & 3, kk = (c >> 8) & 7, wv = c >> 11;
    const int d = wv * 64 + ni * 16 + (lane & 15);
    const int f = kk * 32 + (lane >> 4) * 8;
    const float* sp = src + d * 256 + f;
    unsigned short h[8];
#pragma unroll
    for (int j = 0; j < 8; ++j) h[j] = f2bf(sp[j]);
    *(uint4*)(dst + c * 8) = *(const uint4*)h;
}

// ---------------- kernel 1: fused proj(atom+neighbor) + GATv2 attn + LN ------
struct Smem2 {
    union {
        char  a[48 * 512];      // bf16 A-tile: rows 0-31 neighbors, 32-33 atoms
        float nf[32][264];      // projected neighbors (+pad for aligned float4)
    } u;
    float af[2][256];
    float wal[64];
    float attw[2][4][16];
    float red[4][2][2];         // [wave][atom][sum, sumsq]
};

__global__ __launch_bounds__(256, 3) void gat_fused(
        const float* __restrict__ atomf, const float* __restrict__ nei,
        const unsigned short* __restrict__ wn_p, const unsigned short* __restrict__ wa_p,
        const float* __restrict__ b_n, const float* __restrict__ b_a,
        const float* __restrict__ smask, const float* __restrict__ amask,
        const float* __restrict__ w_align, const float* __restrict__ b_align,
        const float* __restrict__ gamma, const float* __restrict__ beta,
        float* __restrict__ out) {
    __shared__ Smem2 s;
    const int tid = threadIdx.x;
    const int p = blockIdx.x;            // pair of atoms: 2p, 2p+1

    if (tid < 64) s.wal[tid] = w_align[tid];

    // ---- stage neighbors (rows 0..31) fp32 -> swizzled bf16 LDS ----
    const float4* src4 = (const float4*)(nei + (size_t)p * 32 * 256);
#pragma unroll
    for (int j = 0; j < 8; ++j) {
        const int idx4 = tid + j * 256;
        const float4 v = src4[idx4];
        const int r = idx4 >> 6;
        const int byt = (idx4 & 63) * 8;
        ushort4 h;
        h.x = f2bf(v.x); h.y = f2bf(v.y); h.z = f2bf(v.z); h.w = f2bf(v.w);
        *(ushort4*)(s.u.a + r * 512 + (byt ^ ((r & 7) << 4))) = h;
    }
    // ---- stage atoms (rows 32,33) ----
    if (tid < 128) {
        const int at = tid >> 6, cc = tid & 63;
        const float4 v = *(const float4*)(atomf + (size_t)(p * 2 + at) * 256 + cc * 4);
        const int r = 32 + at;
        ushort4 h;
        h.x = f2bf(v.x); h.y = f2bf(v.y); h.z = f2bf(v.z); h.w = f2bf(v.w);
        *(ushort4*)(s.u.a + r * 512 + ((cc * 8) ^ ((r & 7) << 4))) = h;
    }
    __syncthreads();

    const int lane = tid & 63, wv = tid >> 6, l15 = lane & 15, lg = lane >> 4;

    f32x4 acc[3][4];
#pragma unroll
    for (int mi = 0; mi < 3; ++mi)
#pragma unroll
        for (int ni = 0; ni < 4; ++ni)
#pragma unroll
            for (int j = 0; j < 4; ++j) acc[mi][ni][j] = 0.f;

    // ---- K-loop: coalesced permuted-W frags, double-buffered ----
    const unsigned short* wn_wv = wn_p + wv * 16384 + lane * 8;
    const unsigned short* wa_wv = wa_p + wv * 16384 + lane * 8;
    bf16x8 cn[4], ca[4];
#pragma unroll
    for (int ni = 0; ni < 4; ++ni) {
        cn[ni] = *(const bf16x8*)(wn_wv + ni * 512);
        ca[ni] = *(const bf16x8*)(wa_wv + ni * 512);
    }
#pragma unroll
    for (int kk = 0; kk < 8; ++kk) {
        bf16x8 nn[4], na[4];
        if (kk < 7) {
#pragma unroll
            for (int ni = 0; ni < 4; ++ni) {
                nn[ni] = *(const bf16x8*)(wn_wv + (kk + 1) * 2048 + ni * 512);
                na[ni] = *(const bf16x8*)(wa_wv + (kk + 1) * 2048 + ni * 512);
            }
        }
        const int fb = (kk * 32 + lg * 8) * 2;   // byte offset within A row
        bf16x8 afr[3];
#pragma unroll
        for (int mi = 0; mi < 3; ++mi) {
            const int r = mi * 16 + l15;
            afr[mi] = *(const bf16x8*)(s.u.a + r * 512 + (fb ^ ((r & 7) << 4)));
        }
#pragma unroll
        for (int ni = 0; ni < 4; ++ni) {
            acc[0][ni] = __builtin_amdgcn_mfma_f32_16x16x32_bf16(afr[0], cn[ni], acc[0][ni], 0, 0, 0);
            acc[1][ni] = __builtin_amdgcn_mfma_f32_16x16x32_bf16(afr[1], cn[ni], acc[1][ni], 0, 0, 0);
            acc[2][ni] = __builtin_amdgcn_mfma_f32_16x16x32_bf16(afr[2], ca[ni], acc[2][ni], 0, 0, 0);
        }
        if (kk < 7) {
#pragma unroll
            for (int ni = 0; ni < 4; ++ni) { cn[ni] = nn[ni]; ca[ni] = na[ni]; }
        }
    }
    __syncthreads();   // all waves done with u.a before nf overwrite

    // ---- acc -> LDS: nf (+b_n), af (+b_a). C/D map: row = lg*4+j, col = l15.
#pragma unroll
    for (int ni = 0; ni < 4; ++ni) {
        const int d = wv * 64 + ni * 16 + l15;
        const float bnv = b_n[d], bav = b_a[d];
#pragma unroll
        for (int j = 0; j < 4; ++j) {
            s.u.nf[lg * 4 + j][d]      = acc[0][ni][j] + bnv;
            s.u.nf[16 + lg * 4 + j][d] = acc[1][ni][j] + bnv;
        }
        if (lg == 0) {
            s.af[0][d] = acc[2][ni][0] + bav;
            s.af[1][d] = acc[2][ni][1] + bav;
        }
    }
    __syncthreads();

    // ---- scores + masked softmax over k (16 lanes per (atom, head)) ----
    if (tid < 128) {
        const int a = tid >> 6, h = (tid >> 4) & 3, k = tid & 15;
        const float4* af4 = (const float4*)(&s.af[a][h * 64]);
        const float4* nf4 = (const float4*)(&s.u.nf[a * 16 + k][h * 64]);
        const float4* wl4 = (const float4*)(s.wal);
        float sc = 0.f;
#pragma unroll
        for (int i = 0; i < 16; ++i) {
            const float4 x = af4[i], y = nf4[i], w = wl4[i];
            float z0 = x.x + y.x, z1 = x.y + y.y, z2 = x.z + y.z, z3 = x.w + y.w;
            z0 = fmaxf(z0, 0.2f * z0); z1 = fmaxf(z1, 0.2f * z1);
            z2 = fmaxf(z2, 0.2f * z2); z3 = fmaxf(z3, 0.2f * z3);
            sc = fmaf(z0, w.x, sc); sc = fmaf(z1, w.y, sc);
            sc = fmaf(z2, w.z, sc); sc = fmaf(z3, w.w, sc);
        }
        sc += b_align[0] + smask[p * 32 + a * 16 + k];
        float mx = sc;
#pragma unroll
        for (int o = 1; o < 16; o <<= 1) mx = fmaxf(mx, __shfl_xor(mx, o));
        const float e = __expf(sc - mx);
        float sm = e;
#pragma unroll
        for (int o = 1; o < 16; o <<= 1) sm += __shfl_xor(sm, o);
        s.attw[a][h][k] = (e / sm) * amask[p * 32 + a * 16 + k];
    }
    __syncthreads();

    // ---- ctx + LayerNorm (both atoms, single reduction barrier) ----
    const int d = tid, hh = d >> 6;
    float c0 = 0.f, c1 = 0.f;
#pragma unroll
    for (int k = 0; k < 16; ++k) c0 = fmaf(s.attw[0][hh][k], s.u.nf[k][d], c0);
#pragma unroll
    for (int k = 0; k < 16; ++k) c1 = fmaf(s.attw[1][hh][k], s.u.nf[16 + k][d], c1);
    float sm0 = c0, sq0 = c0 * c0, sm1 = c1, sq1 = c1 * c1;
#pragma unroll
    for (int o = 1; o < 64; o <<= 1) {
        sm0 += __shfl_xor(sm0, o); sq0 += __shfl_xor(sq0, o);
        sm1 += __shfl_xor(sm1, o); sq1 += __shfl_xor(sq1, o);
    }
    if (lane == 0) {
        s.red[wv][0][0] = sm0; s.red[wv][0][1] = sq0;
        s.red[wv][1][0] = sm1; s.red[wv][1][1] = sq1;
    }
    __syncthreads();
    float ts0 = 0.f, tq0 = 0.f, ts1 = 0.f, tq1 = 0.f;
#pragma unroll
    for (int q = 0; q < 4; ++q) {
        ts0 += s.red[q][0][0]; tq0 += s.red[q][0][1];
        ts1 += s.red[q][1][0]; tq1 += s.red[q][1][1];
    }
    const float g = gamma[d], be = beta[d];
    const float mu0 = ts0 * (1.f / 256.f), mu1 = ts1 * (1.f / 256.f);
    const float v0 = fmaxf(tq0 * (1.f / 256.f) - mu0 * mu0, 0.f);
    const float v1 = fmaxf(tq1 * (1.f / 256.f) - mu1 * mu1, 0.f);
    out[(size_t)(p * 2) * 256 + d]     = (c0 - mu0) * rsqrtf(v0 + 1e-5f) * g + be;
    out[(size_t)(p * 2 + 1) * 256 + d] = (c1 - mu1) * rsqrtf(v1 + 1e-5f) * g + be;
}

extern "C" void kernel_launch(void* const* d_in, const int* in_sizes, int n_in,
                              void* d_out, int out_size, void* d_ws, size_t ws_size,
                              hipStream_t stream) {
    const float* atomf = (const float*)d_in[0];
    const float* nei   = (const float*)d_in[1];
    const float* smask = (const float*)d_in[2];
    const float* amask = (const float*)d_in[3];
    const float* Wa    = (const float*)d_in[4];
    const float* ba    = (const float*)d_in[5];
    const float* Wn    = (const float*)d_in[6];
    const float* bn    = (const float*)d_in[7];
    const float* wal   = (const float*)d_in[8];
    const float* bal   = (const float*)d_in[9];
    const float* gam   = (const float*)d_in[10];
    const float* bet   = (const float*)d_in[11];
    float* out = (float*)d_out;

    char* ws = (char*)d_ws;
    unsigned short* wa_bf = (unsigned short*)ws;             // 128 KiB
    unsigned short* wn_bf = (unsigned short*)(ws + 131072);  // 128 KiB

    hipLaunchKernelGGL(conv_w, dim3(64), dim3(256), 0, stream,
                       Wa, Wn, wa_bf, wn_bf);
    hipLaunchKernelGGL(gat_fused, dim3(2048), dim3(256), 0, stream,
                       atomf, nei, wn_bf, wa_bf, bn, ba, smask, amask,
                       wal, bal, gam, bet, out);
}

// Round 6
// 136.523 us; speedup vs baseline: 1.1885x; 1.0463x over previous
//
#include <hip/hip_runtime.h>
#include <hip/hip_bf16.h>

// B=32, N=128, K=16, F=D=256, H=4, DK=64
// out[4096,256] fp32.

typedef float f32x4 __attribute__((ext_vector_type(4)));
typedef __bf16 bf16x8 __attribute__((ext_vector_type(8)));

__device__ __forceinline__ unsigned short f2bf(float x) {
    unsigned int u = __float_as_uint(x);
    u += 0x7FFFu + ((u >> 16) & 1u);   // round-to-nearest-even
    return (unsigned short)(u >> 16);
}

// ---------------- kernel 0: convert + permute weights to MFMA B-frag order ----
// chunk c = ((wv*8 + kk)*4 + ni)*64 + lane holds
//   W[d = wv*64 + ni*16 + (lane&15)][f = kk*32 + (lane>>4)*8 .. +8)
__global__ __launch_bounds__(256) void conv_w(const float* __restrict__ wa,
                                              const float* __restrict__ wn,
                                              unsigned short* __restrict__ owa,
                                              unsigned short* __restrict__ own) {
    const int g = blockIdx.x * 256 + threadIdx.x;     // 0..16383
    const float* src = (g & 8192) ? wn : wa;
    unsigned short* dst = (g & 8192) ? own : owa;
    const int c = g & 8191;
    const int lane = c & 63, ni = (c >> 6) & 3, kk = (c >> 8) & 7, wv = c >> 11;
    const int d = wv * 64 + ni * 16 + (lane & 15);
    const int f = kk * 32 + (lane >> 4) * 8;
    const float* sp = src + d * 256 + f;
    unsigned short h[8];
#pragma unroll
    for (int j = 0; j < 8; ++j) h[j] = f2bf(sp[j]);
    *(uint4*)(dst + c * 8) = *(const uint4*)h;
}

// ---------------- kernel 1: af = atom_feature @ W_a^T + b_a  (16 atoms/block) --
__global__ __launch_bounds__(256) void proj_atoms(const float* __restrict__ atomf,
                                                  const unsigned short* __restrict__ wa_p,
                                                  const float* __restrict__ b_a,
                                                  float* __restrict__ af) {
    __shared__ char lds[16 * 512];
    const int tid = threadIdx.x, p = blockIdx.x;   // 256 blocks
    const float4* src4 = (const float4*)(atomf + (size_t)p * 16 * 256);
#pragma unroll
    for (int j = 0; j < 4; ++j) {
        const int idx4 = tid + j * 256;            // 1024 float4 = 16 rows
        const float4 v = src4[idx4];
        const int r = idx4 >> 6, byt = (idx4 & 63) * 8;
        ushort4 h;
        h.x = f2bf(v.x); h.y = f2bf(v.y); h.z = f2bf(v.z); h.w = f2bf(v.w);
        *(ushort4*)(lds + r * 512 + (byt ^ ((r & 7) << 4))) = h;
    }
    __syncthreads();
    const int lane = tid & 63, wv = tid >> 6, l15 = lane & 15, lg = lane >> 4;
    f32x4 acc[4];
#pragma unroll
    for (int ni = 0; ni < 4; ++ni)
#pragma unroll
        for (int j = 0; j < 4; ++j) acc[ni][j] = 0.f;
    const unsigned short* w = wa_p + wv * 16384 + lane * 8;
#pragma unroll
    for (int kk = 0; kk < 8; ++kk) {
        const int fb = (kk * 32 + lg * 8) * 2;
        const int r = l15;
        const bf16x8 afr = *(const bf16x8*)(lds + r * 512 + (fb ^ ((r & 7) << 4)));
#pragma unroll
        for (int ni = 0; ni < 4; ++ni) {
            const bf16x8 cn = *(const bf16x8*)(w + kk * 2048 + ni * 512);
            acc[ni] = __builtin_amdgcn_mfma_f32_16x16x32_bf16(afr, cn, acc[ni], 0, 0, 0);
        }
    }
#pragma unroll
    for (int ni = 0; ni < 4; ++ni) {
        const int d = wv * 64 + ni * 16 + l15;
        const float bav = b_a[d];
#pragma unroll
        for (int j = 0; j < 4; ++j)
            af[(size_t)(p * 16 + lg * 4 + j) * 256 + d] = acc[ni][j] + bav;
    }
}

// ---------------- kernel 2: fused neighbor proj + GATv2 attn + LN (4 atoms) ----
struct SmemG {
    char  a[64 * 512];        // bf16 A-tile, XOR-swizzled (32 KB)
    float af[4][256];         // projected atoms (+bias)
    float wal[64];
    float sm[4][16];
    float am[4][16];
    float red[4][4][2];       // [wave][atom][sum, sumsq]
};

__global__ __launch_bounds__(256, 4) void gat4(
        const float* __restrict__ nei, const float* __restrict__ af_buf,
        const unsigned short* __restrict__ wn_p, const float* __restrict__ b_n,
        const float* __restrict__ smask, const float* __restrict__ amask,
        const float* __restrict__ w_align, const float* __restrict__ b_align,
        const float* __restrict__ gamma, const float* __restrict__ beta,
        float* __restrict__ out) {
    __shared__ SmemG s;
    const int tid = threadIdx.x;
    const int p = blockIdx.x;            // atoms 4p..4p+3, neighbor rows 64p..64p+63

    // ---- stage 64 neighbor rows fp32 -> swizzled bf16 LDS ----
    const float4* src4 = (const float4*)(nei + (size_t)p * 64 * 256);
#pragma unroll
    for (int j = 0; j < 16; ++j) {
        const int idx4 = tid + j * 256;          // 4096 float4
        const float4 v = src4[idx4];
        const int r = idx4 >> 6, byt = (idx4 & 63) * 8;
        ushort4 h;
        h.x = f2bf(v.x); h.y = f2bf(v.y); h.z = f2bf(v.z); h.w = f2bf(v.w);
        *(ushort4*)(s.a + r * 512 + (byt ^ ((r & 7) << 4))) = h;
    }
#pragma unroll
    for (int a2 = 0; a2 < 4; ++a2)
        s.af[a2][tid] = af_buf[(size_t)p * 1024 + a2 * 256 + tid];
    if (tid < 64) {
        s.wal[tid] = w_align[tid];
        ((float*)s.sm)[tid] = smask[p * 64 + tid];
        ((float*)s.am)[tid] = amask[p * 64 + tid];
    }
    __syncthreads();

    const int lane = tid & 63, wv = tid >> 6, l15 = lane & 15, lg = lane >> 4;

    f32x4 acc[4][4];                     // [atom(M-tile)][ni]
#pragma unroll
    for (int a = 0; a < 4; ++a)
#pragma unroll
        for (int ni = 0; ni < 4; ++ni)
#pragma unroll
            for (int j = 0; j < 4; ++j) acc[a][ni][j] = 0.f;

    const unsigned short* w = wn_p + wv * 16384 + lane * 8;
#pragma unroll
    for (int kk = 0; kk < 8; ++kk) {
        const int fb = (kk * 32 + lg * 8) * 2;
        bf16x8 afr[4];
#pragma unroll
        for (int a = 0; a < 4; ++a) {
            const int r = a * 16 + l15;
            afr[a] = *(const bf16x8*)(s.a + r * 512 + (fb ^ ((r & 7) << 4)));
        }
#pragma unroll
        for (int ni = 0; ni < 4; ++ni) {
            const bf16x8 cn = *(const bf16x8*)(w + kk * 2048 + ni * 512);
#pragma unroll
            for (int a = 0; a < 4; ++a)
                acc[a][ni] = __builtin_amdgcn_mfma_f32_16x16x32_bf16(afr[a], cn, acc[a][ni], 0, 0, 0);
        }
    }

    // ---- register epilogue. lane holds nf[atom a][k=lg*4+j][d=wv*64+ni*16+l15]
    float bn4[4], wl4[4];
#pragma unroll
    for (int ni = 0; ni < 4; ++ni) {
        bn4[ni] = b_n[wv * 64 + ni * 16 + l15];
        wl4[ni] = s.wal[ni * 16 + l15];        // w_align is per-head-relative (DK=64)
    }
#pragma unroll
    for (int a = 0; a < 4; ++a)
#pragma unroll
        for (int ni = 0; ni < 4; ++ni)
#pragma unroll
            for (int j = 0; j < 4; ++j) acc[a][ni][j] += bn4[ni];   // nf += b_n

    const float bal = b_align[0];
    float ctx[4][4];
#pragma unroll
    for (int a = 0; a < 4; ++a) {
        float afd[4];
#pragma unroll
        for (int ni = 0; ni < 4; ++ni)
            afd[ni] = s.af[a][wv * 64 + ni * 16 + l15];   // FIX: head offset wv*64
        // head h = wv: score over this wave's 64 d's only
        float sj[4];
#pragma unroll
        for (int j = 0; j < 4; ++j) {
            float t = 0.f;
#pragma unroll
            for (int ni = 0; ni < 4; ++ni) {
                float z = afd[ni] + acc[a][ni][j];
                z = fmaxf(z, 0.2f * z);                 // LeakyReLU(0.2)
                t = fmaf(z, wl4[ni], t);
            }
            sj[j] = t;
        }
#pragma unroll
        for (int j = 0; j < 4; ++j) {
#pragma unroll
            for (int o = 1; o < 16; o <<= 1) sj[j] += __shfl_xor(sj[j], o);
            sj[j] += bal + s.sm[a][lg * 4 + j];
        }
        float m = fmaxf(fmaxf(sj[0], sj[1]), fmaxf(sj[2], sj[3]));
        m = fmaxf(m, __shfl_xor(m, 16));
        m = fmaxf(m, __shfl_xor(m, 32));
        float e[4], sum = 0.f;
#pragma unroll
        for (int j = 0; j < 4; ++j) { e[j] = __expf(sj[j] - m); sum += e[j]; }
        sum += __shfl_xor(sum, 16);
        sum += __shfl_xor(sum, 32);
        const float inv = 1.f / sum;
        float aw[4];
#pragma unroll
        for (int j = 0; j < 4; ++j) aw[j] = e[j] * inv * s.am[a][lg * 4 + j];
        // ctx[d] = sum_k attw[k] * nf[k][d]
#pragma unroll
        for (int ni = 0; ni < 4; ++ni) {
            float c = 0.f;
#pragma unroll
            for (int j = 0; j < 4; ++j) c = fmaf(aw[j], acc[a][ni][j], c);
            c += __shfl_xor(c, 16);
            c += __shfl_xor(c, 32);
            ctx[a][ni] = c;
        }
        // LN partials for this wave's 64 d's
        float t = 0.f, q = 0.f;
#pragma unroll
        for (int ni = 0; ni < 4; ++ni) { t += ctx[a][ni]; q = fmaf(ctx[a][ni], ctx[a][ni], q); }
#pragma unroll
        for (int o = 1; o < 16; o <<= 1) { t += __shfl_xor(t, o); q += __shfl_xor(q, o); }
        if (lane == 0) { s.red[wv][a][0] = t; s.red[wv][a][1] = q; }
    }
    __syncthreads();

    const float g = gamma[wv * 64 + lane];
    const float be = beta[wv * 64 + lane];
#pragma unroll
    for (int a = 0; a < 4; ++a) {
        float ts = 0.f, tq = 0.f;
#pragma unroll
        for (int q2 = 0; q2 < 4; ++q2) { ts += s.red[q2][a][0]; tq += s.red[q2][a][1]; }
        const float mu = ts * (1.f / 256.f);
        float var = tq * (1.f / 256.f) - mu * mu;
        var = fmaxf(var, 0.f);
        const float rs = rsqrtf(var + 1e-5f);
        const float cv = (lg == 0) ? ctx[a][0] : (lg == 1) ? ctx[a][1]
                        : (lg == 2) ? ctx[a][2] : ctx[a][3];
        out[(size_t)(p * 4 + a) * 256 + wv * 64 + lane] = (cv - mu) * rs * g + be;
    }
}

extern "C" void kernel_launch(void* const* d_in, const int* in_sizes, int n_in,
                              void* d_out, int out_size, void* d_ws, size_t ws_size,
                              hipStream_t stream) {
    const float* atomf = (const float*)d_in[0];
    const float* nei   = (const float*)d_in[1];
    const float* smask = (const float*)d_in[2];
    const float* amask = (const float*)d_in[3];
    const float* Wa    = (const float*)d_in[4];
    const float* ba    = (const float*)d_in[5];
    const float* Wn    = (const float*)d_in[6];
    const float* bn    = (const float*)d_in[7];
    const float* wal   = (const float*)d_in[8];
    const float* bal   = (const float*)d_in[9];
    const float* gam   = (const float*)d_in[10];
    const float* bet   = (const float*)d_in[11];
    float* out = (float*)d_out;

    char* ws = (char*)d_ws;
    float*          af_buf = (float*)ws;                               // 4 MiB
    unsigned short* wa_bf  = (unsigned short*)(ws + 4194304);          // 128 KiB
    unsigned short* wn_bf  = (unsigned short*)(ws + 4194304 + 131072); // 128 KiB

    hipLaunchKernelGGL(conv_w, dim3(64), dim3(256), 0, stream,
                       Wa, Wn, wa_bf, wn_bf);
    hipLaunchKernelGGL(proj_atoms, dim3(256), dim3(256), 0, stream,
                       atomf, wa_bf, ba, af_buf);
    hipLaunchKernelGGL(gat4, dim3(1024), dim3(256), 0, stream,
                       nei, af_buf, wn_bf, bn, smask, amask,
                       wal, bal, gam, bet, out);
}